// Round 10
// baseline (323.340 us; speedup 1.0000x reference)
//
#include <hip/hip_runtime.h>

#define NVV   778
#define NSEG  16
#define SEGSZ 49
#define GRIDN 32
#define BATCH 128
#define NPTS  (NSEG * SEGSZ)           // 784
#define VOLSZ (GRIDN * GRIDN * GRIDN)  // 32768 floats = 128 KB
#define NBLK  256
#define VPB   16                        // volumes per persistent block

// clean 16/16 z-split, no duplicate slab:
//   R0 = slabs 0..15, R1 = slabs 16..31 (64 KB each)
#define HF (16 * 1024)                  // floats per half

typedef __attribute__((address_space(1))) const void* as1_t;
typedef __attribute__((address_space(3))) void* as3_t;

// 64 x 1KB chunks per half; each of 16 waves issues exactly 4 DMAs.
#define STREAM(DST, SRC) \
    { _Pragma("unroll") \
      for (int c_ = 0; c_ < 4; ++c_) { \
        int ch_ = c_ * 16 + wv; \
        __builtin_amdgcn_global_load_lds( \
            (as1_t)((SRC) + ch_ * 256 + lane * 4), \
            (as3_t)((DST) + ch_ * 256), 16, 0, 0); \
      } }

// 2x2 xy-taps within one z-slab
__device__ __forceinline__ float tapxy(const float* slab, int x0, int y0,
                                       float wx, float wy)
{
    float s = 0.f;
    #pragma unroll
    for (int dy = 0; dy < 2; ++dy) {
        int yy = y0 + dy;
        if (yy < 0 || yy >= GRIDN) continue;
        float wyv = dy ? wy : 1.f - wy;
        const float* row = slab + yy * GRIDN;
        #pragma unroll
        for (int dx = 0; dx < 2; ++dx) {
            int xx = x0 + dx;
            if (xx < 0 || xx >= GRIDN) continue;
            s += wyv * (dx ? wx : 1.f - wx) * row[xx];
        }
    }
    return s;
}

// Persistent: 256 blocks x 1024 threads (1 block/CU, 128 KB LDS).
// 2-buffer ring, one z-half streamed per phase, tapped next phase:
//   phase A: STREAM(R1 <- h1(v));   tap slabs <=15 from R0;  barrier
//   phase B: STREAM(R0 <- h0(v+1)); tap slabs >=16 from R1;  wave-atomic; barrier
// 2 barriers/volume, no block reduction, no duplicated slab. acc carries
// across phases (z0==15 straddles: dz0 tap in A, dz1 tap in B).
__global__ __launch_bounds__(1024, 4) void sample_kernel(
    const float* __restrict__ vertices, const int* __restrict__ seg,
    const float* __restrict__ phiR, const float* __restrict__ phiL,
    float* __restrict__ loss)
{
    __shared__ __align__(16) float R0[HF];
    __shared__ __align__(16) float R1[HF];
    __shared__ float4 sbox[VPB];

    const int tid  = threadIdx.x;
    const int bx   = blockIdx.x;
    const int k    = bx & (NSEG - 1);    // constant per block (256 % 16 == 0)
    const int wv   = tid >> 6;
    const int lane = tid & 63;

    auto phiPtr = [&](int it) {
        int vid  = bx + NBLK * it;
        int b    = (vid >> 4) & (BATCH - 1);
        int pass = vid >> 11;            // NSEG*BATCH = 2048
        return (pass == 0 ? phiR : phiL) + ((size_t)k * BATCH + b) * VOLSZ;
    };

    // ---- prologue: scattered loads first, then the DMA burst ----
    int pvi = (tid < NPTS) ? seg[tid] : 0;

    // box inputs: wave wv handles volume wv's box
    int vidw    = bx + NBLK * wv;
    int bbw     = (vidw >> 4) & (BATCH - 1);
    int boxSide = ((vidw >> 11) == 0) ? 0 : 1;   // opposite of sampled side
    bool bact   = lane < SEGSZ;
    int bvi     = bact ? seg[k * SEGSZ + lane] : 0;
    const float* bvp = vertices + (((size_t)bbw * 2 + boxSide) * NVV + bvi) * 3;
    float bxx = bvp[0], bxy = bvp[1], bxz = bvp[2];

    // volume-0 point coords
    float pvx = 0.f, pvy = 0.f, pvz = 0.f;
    if (tid < NPTS) {
        int srcS = 1;                    // pass 0 samples LEFT vertices
        int b0   = (bx >> 4) & (BATCH - 1);
        const float* v = vertices + (((size_t)b0 * 2 + srcS) * NVV + pvi) * 3;
        pvx = v[0]; pvy = v[1]; pvz = v[2];
    }

    STREAM(R0, phiPtr(0))                // h0 of volume 0

    // box shfl-reduce (waits box loads via counted vmcnt; DMAs stay in flight)
    {
        float mnx = bact ? bxx : 1e30f, mxx = bact ? bxx : -1e30f;
        float mny = bact ? bxy : 1e30f, mxy = bact ? bxy : -1e30f;
        float mnz = bact ? bxz : 1e30f, mxz = bact ? bxz : -1e30f;
        #pragma unroll
        for (int m = 32; m; m >>= 1) {
            mnx = fminf(mnx, __shfl_xor(mnx, m));
            mxx = fmaxf(mxx, __shfl_xor(mxx, m));
            mny = fminf(mny, __shfl_xor(mny, m));
            mxy = fmaxf(mxy, __shfl_xor(mxy, m));
            mnz = fminf(mnz, __shfl_xor(mnz, m));
            mxz = fmaxf(mxz, __shfl_xor(mxz, m));
        }
        if (lane == 0) {
            float ext = fmaxf(fmaxf(mxx - mnx, mxy - mny), mxz - mnz);
            sbox[wv] = make_float4(0.5f * (mnx + mxx), 0.5f * (mny + mxy),
                                   0.5f * (mnz + mxz), 1.0f / (0.55f * ext));
        }
    }

    __syncthreads();   // R0 resident, sbox visible

    float nvx = 0.f, nvy = 0.f, nvz = 0.f;

    for (int v = 0; v < VPB; ++v) {
        const bool more = (v + 1 < VPB);

        // ================= phase A =================
        STREAM(R1, phiPtr(v) + HF)       // h1 of current volume

        // per-volume setup (pv + sbox resident; no stream-drain needed)
        float fx = 0.f, fy = 0.f, fz = -2.f;
        if (tid < NPTS) {
            float4 b4 = sbox[v];
            fx = ((pvx - b4.x) * b4.w + 1.f) * 15.5f;
            fy = ((pvy - b4.y) * b4.w + 1.f) * 15.5f;
            fz = ((pvz - b4.z) * b4.w + 1.f) * 15.5f;
        }
        bool active = (fx > -1.f && fx < 32.f && fy > -1.f && fy < 32.f &&
                       fz > -1.f && fz < 32.f);
        float x0f = floorf(fx), y0f = floorf(fy), z0f = floorf(fz);
        float wx = fx - x0f, wy = fy - y0f, wz = fz - z0f;
        int x0 = (int)x0f, y0 = (int)y0f, z0 = (int)z0f;

        float acc = 0.f;
        if (active && z0 <= 15) {        // slabs <=15 live in R0
            if (z0 >= 0)
                acc += (1.f - wz) * tapxy(R0 + z0 * 1024, x0, y0, wx, wy);
            if (z0 <= 14)
                acc += wz * tapxy(R0 + (z0 + 1) * 1024, x0, y0, wx, wy);
        }

        __syncthreads();   // A-end: R1 resident; R0 consumed

        // ================= phase B =================
        // next volume's point coords (issued BEFORE the DMA burst so the
        // wait for them never drains the stream)
        if (more && tid < NPTS) {
            int vid  = bx + NBLK * (v + 1);
            int b_   = (vid >> 4) & (BATCH - 1);
            int srcS = (vid >> 11) == 0 ? 1 : 0;
            const float* vp = vertices + (((size_t)b_ * 2 + srcS) * NVV + pvi) * 3;
            nvx = vp[0]; nvy = vp[1]; nvz = vp[2];
        }
        if (more) { STREAM(R0, phiPtr(v + 1)) }   // h0 of next volume

        if (active && z0 >= 15) {        // slabs >=16 live in R1
            if (z0 >= 16)
                acc += (1.f - wz) * tapxy(R1 + (z0 - 16) * 1024, x0, y0, wx, wy);
            if (z0 <= 30)
                acc += wz * tapxy(R1 + (z0 - 15) * 1024, x0, y0, wx, wy);
        }

        // per-wave reduce + one atomic per wave (no block reduction barrier)
        #pragma unroll
        for (int off = 32; off; off >>= 1)
            acc += __shfl_down(acc, off);
        if (lane == 0) {
            int vid = bx + NBLK * v;
            atomicAdd(loss + ((vid >> 4) & (BATCH - 1)), acc * 0.25f);
        }

        __syncthreads();   // B-end: R0 resident; R1 consumed
        pvx = nvx; pvy = nvy; pvz = nvz;
    }
}

extern "C" void kernel_launch(void* const* d_in, const int* in_sizes, int n_in,
                              void* d_out, int out_size, void* d_ws, size_t ws_size,
                              hipStream_t stream) {
    const float* vertices = (const float*)d_in[0];
    const float* phiR     = (const float*)d_in[1];
    const float* phiL     = (const float*)d_in[2];
    const int*   seg      = (const int*)d_in[3];
    float* loss = (float*)d_out;

    hipMemsetAsync(d_out, 0, (size_t)out_size * sizeof(float), stream);

    sample_kernel<<<NBLK, 1024, 0, stream>>>(vertices, seg, phiR, phiL, loss);
}

// Round 11
// 107.677 us; speedup vs baseline: 3.0029x; 3.0029x over previous
//
#include <hip/hip_runtime.h>

#define NVV   778
#define NSEG  16
#define SEGSZ 49
#define GRIDN 32
#define BATCH 128
#define NPTS  (NSEG * SEGSZ)           // 784
#define VOLSZ (GRIDN * GRIDN * GRIDN)  // 32768 floats = 128 KB
#define NBLK  256
#define VPB   16                        // volumes per persistent block

// clean 16/16 z-split, no duplicate slab:
//   R0 = slabs 0..15, R1 = slabs 16..31 (64 KB each)
#define HF (16 * 1024)

typedef __attribute__((address_space(1))) const void* as1_t;
typedef __attribute__((address_space(3))) void* as3_t;

// 64 x 1KB chunks per half; each of 16 waves issues exactly 4 DMAs.
#define STREAM(DST, SRC) \
    { _Pragma("unroll") \
      for (int c_ = 0; c_ < 4; ++c_) { \
        int ch_ = c_ * 16 + wv; \
        __builtin_amdgcn_global_load_lds( \
            (as1_t)((SRC) + ch_ * 256 + lane * 4), \
            (as3_t)((DST) + ch_ * 256), 16, 0, 0); \
      } }

// 2x2 xy-taps within one z-slab
__device__ __forceinline__ float tapxy(const float* slab, int x0, int y0,
                                       float wx, float wy)
{
    float s = 0.f;
    #pragma unroll
    for (int dy = 0; dy < 2; ++dy) {
        int yy = y0 + dy;
        if (yy < 0 || yy >= GRIDN) continue;
        float wyv = dy ? wy : 1.f - wy;
        const float* row = slab + yy * GRIDN;
        #pragma unroll
        for (int dx = 0; dx < 2; ++dx) {
            int xx = x0 + dx;
            if (xx < 0 || xx >= GRIDN) continue;
            s += wyv * (dx ? wx : 1.f - wx) * row[xx];
        }
    }
    return s;
}

// Persistent: 256 blocks x 1024 threads (1 block/CU, ~128 KB LDS).
// Per volume: phase A streams h1(v) while tapping slabs<=15 from R0 and
// firing the PREVIOUS volume's single deferred atomic; phase B streams
// h0(v+1) while tapping slabs>=16 from R1 and writing wsum. 2 barriers +
// exactly 1 atomic per volume (R10 lesson: 16 atomics/volume to a hot
// address = 256-wave serialization on one L2 line = 3x regression).
__global__ __launch_bounds__(1024, 4) void sample_kernel(
    const float* __restrict__ vertices, const int* __restrict__ seg,
    const float* __restrict__ phiR, const float* __restrict__ phiL,
    float* __restrict__ loss)
{
    __shared__ __align__(16) float R0[HF];
    __shared__ __align__(16) float R1[HF];
    __shared__ float4 sbox[VPB];
    __shared__ float wsum[16];

    const int tid  = threadIdx.x;
    const int bx   = blockIdx.x;
    const int k    = bx & (NSEG - 1);    // constant per block (256 % 16 == 0)
    const int wv   = tid >> 6;
    const int lane = tid & 63;

    auto phiPtr = [&](int it) {
        int vid  = bx + NBLK * it;
        int b    = (vid >> 4) & (BATCH - 1);
        int pass = vid >> 11;            // NSEG*BATCH = 2048
        return (pass == 0 ? phiR : phiL) + ((size_t)k * BATCH + b) * VOLSZ;
    };

    // ---- prologue: scattered loads first, then the DMA burst ----
    int pvi = (tid < NPTS) ? seg[tid] : 0;

    int vidw    = bx + NBLK * wv;
    int bbw     = (vidw >> 4) & (BATCH - 1);
    int boxSide = ((vidw >> 11) == 0) ? 0 : 1;   // opposite of sampled side
    bool bact   = lane < SEGSZ;
    int bvi     = bact ? seg[k * SEGSZ + lane] : 0;
    const float* bvp = vertices + (((size_t)bbw * 2 + boxSide) * NVV + bvi) * 3;
    float bxx = bvp[0], bxy = bvp[1], bxz = bvp[2];

    float pvx = 0.f, pvy = 0.f, pvz = 0.f;
    if (tid < NPTS) {
        int b0 = (bx >> 4) & (BATCH - 1);
        const float* v = vertices + (((size_t)b0 * 2 + 1) * NVV + pvi) * 3;
        pvx = v[0]; pvy = v[1]; pvz = v[2];   // pass 0 samples LEFT verts
    }

    STREAM(R0, phiPtr(0))                // h0 of volume 0

    // box shfl-reduce (register-only, overlaps the DMA stream)
    {
        float mnx = bact ? bxx : 1e30f, mxx = bact ? bxx : -1e30f;
        float mny = bact ? bxy : 1e30f, mxy = bact ? bxy : -1e30f;
        float mnz = bact ? bxz : 1e30f, mxz = bact ? bxz : -1e30f;
        #pragma unroll
        for (int m = 32; m; m >>= 1) {
            mnx = fminf(mnx, __shfl_xor(mnx, m));
            mxx = fmaxf(mxx, __shfl_xor(mxx, m));
            mny = fminf(mny, __shfl_xor(mny, m));
            mxy = fmaxf(mxy, __shfl_xor(mxy, m));
            mnz = fminf(mnz, __shfl_xor(mnz, m));
            mxz = fmaxf(mxz, __shfl_xor(mxz, m));
        }
        if (lane == 0) {
            float ext = fmaxf(fmaxf(mxx - mnx, mxy - mny), mxz - mnz);
            sbox[wv] = make_float4(0.5f * (mnx + mxx), 0.5f * (mny + mxy),
                                   0.5f * (mnz + mxz), 1.0f / (0.55f * ext));
        }
    }

    __syncthreads();   // R0 resident, sbox visible

    float nvx = 0.f, nvy = 0.f, nvz = 0.f;

    for (int v = 0; v < VPB; ++v) {
        const bool more = (v + 1 < VPB);

        // ================= phase A =================
        // deferred single atomic for volume v-1 (wsum stable: written
        // before last barrier, not rewritten until phase B)
        if (v > 0 && tid == 0) {
            float tot = 0.f;
            #pragma unroll
            for (int i = 0; i < 16; ++i) tot += wsum[i];
            int vidp = bx + NBLK * (v - 1);
            atomicAdd(loss + ((vidp >> 4) & (BATCH - 1)), tot * 0.25f);
        }

        // coords from sbox BEFORE the DMA burst (R7 ordering)
        float fx = 0.f, fy = 0.f, fz = -2.f;
        if (tid < NPTS) {
            float4 b4 = sbox[v];
            fx = ((pvx - b4.x) * b4.w + 1.f) * 15.5f;
            fy = ((pvy - b4.y) * b4.w + 1.f) * 15.5f;
            fz = ((pvz - b4.z) * b4.w + 1.f) * 15.5f;
        }
        bool active = (fx > -1.f && fx < 32.f && fy > -1.f && fy < 32.f &&
                       fz > -1.f && fz < 32.f);
        float x0f = floorf(fx), y0f = floorf(fy), z0f = floorf(fz);
        float wx = fx - x0f, wy = fy - y0f, wz = fz - z0f;
        int x0 = (int)x0f, y0 = (int)y0f, z0 = (int)z0f;

        STREAM(R1, phiPtr(v) + HF)       // h1 of current volume

        float acc = 0.f;
        if (active && z0 <= 15) {        // slabs <=15 live in R0
            if (z0 >= 0)
                acc += (1.f - wz) * tapxy(R0 + z0 * 1024, x0, y0, wx, wy);
            if (z0 <= 14)
                acc += wz * tapxy(R0 + (z0 + 1) * 1024, x0, y0, wx, wy);
        }

        __syncthreads();   // A-end: R1 resident; R0 consumed

        // ================= phase B =================
        if (more && tid < NPTS) {
            int vid  = bx + NBLK * (v + 1);
            int b_   = (vid >> 4) & (BATCH - 1);
            int srcS = (vid >> 11) == 0 ? 1 : 0;
            const float* vp = vertices + (((size_t)b_ * 2 + srcS) * NVV + pvi) * 3;
            nvx = vp[0]; nvy = vp[1]; nvz = vp[2];
        }
        if (more) { STREAM(R0, phiPtr(v + 1)) }   // h0 of next volume

        if (active && z0 >= 15) {        // slabs >=16 live in R1
            if (z0 >= 16)
                acc += (1.f - wz) * tapxy(R1 + (z0 - 16) * 1024, x0, y0, wx, wy);
            if (z0 <= 30)
                acc += wz * tapxy(R1 + (z0 - 15) * 1024, x0, y0, wx, wy);
        }

        // per-wave reduce -> wsum (one ds_write per wave, no extra barrier)
        #pragma unroll
        for (int off = 32; off; off >>= 1)
            acc += __shfl_down(acc, off);
        if (lane == 0) wsum[wv] = acc;

        __syncthreads();   // B-end: R0 resident; R1 consumed; wsum visible
        pvx = nvx; pvy = nvy; pvz = nvz;
    }

    // final volume's atomic
    if (tid == 0) {
        float tot = 0.f;
        #pragma unroll
        for (int i = 0; i < 16; ++i) tot += wsum[i];
        int vidp = bx + NBLK * (VPB - 1);
        atomicAdd(loss + ((vidp >> 4) & (BATCH - 1)), tot * 0.25f);
    }
}

extern "C" void kernel_launch(void* const* d_in, const int* in_sizes, int n_in,
                              void* d_out, int out_size, void* d_ws, size_t ws_size,
                              hipStream_t stream) {
    const float* vertices = (const float*)d_in[0];
    const float* phiR     = (const float*)d_in[1];
    const float* phiL     = (const float*)d_in[2];
    const int*   seg      = (const int*)d_in[3];
    float* loss = (float*)d_out;

    hipMemsetAsync(d_out, 0, (size_t)out_size * sizeof(float), stream);

    sample_kernel<<<NBLK, 1024, 0, stream>>>(vertices, seg, phiR, phiL, loss);
}